// Round 2
// baseline (468.915 us; speedup 1.0000x reference)
//
#include <hip/hip_runtime.h>
#include <cstdint>

#define HIDDEN 128

typedef unsigned short u16;
using frag_t   = __attribute__((ext_vector_type(8))) short;   // 8 bf16 (4 VGPRs)
using f32x4_t  = __attribute__((ext_vector_type(4))) float;   // MFMA accumulator
using ushort8_t = __attribute__((ext_vector_type(8))) unsigned short;

__device__ __forceinline__ float bf2f(u16 u) {
    union { unsigned int i; float f; } c;
    c.i = ((unsigned int)u) << 16;
    return c.f;
}
__device__ __forceinline__ u16 f2bf(float f) {
    unsigned int u = __float_as_uint(f);
    unsigned int r = (u + 0x7fffu + ((u >> 16) & 1u)) >> 16;   // RNE
    return (u16)r;
}

// ---------------- CSR build (edge_index arrives as int32 from harness) ----------------
// XCD-range partitioning: blocks with blockIdx&7==r own dst range [r*npr, (r+1)*npr).

__global__ void k_hist(const int* __restrict__ ei, int E, int* __restrict__ deg, int npr) {
    int r  = blockIdx.x & 7;
    int lo = r * npr, hi = lo + npr;
    int nb = gridDim.x >> 3;
    int bi = blockIdx.x >> 3;
    int tid = bi * blockDim.x + threadIdx.x;
    int stride = nb * blockDim.x;
    if ((E & 3) == 0) {
        const int4* d4 = (const int4*)(ei + E);
        int nch = E >> 2;
        for (int c = tid; c < nch; c += stride) {
            int4 d = d4[c];
            if (d.x >= lo && d.x < hi) atomicAdd(&deg[d.x], 1);
            if (d.y >= lo && d.y < hi) atomicAdd(&deg[d.y], 1);
            if (d.z >= lo && d.z < hi) atomicAdd(&deg[d.z], 1);
            if (d.w >= lo && d.w < hi) atomicAdd(&deg[d.w], 1);
        }
    } else {
        for (int e = tid; e < E; e += stride) {
            int d = ei[E + e];
            if (d >= lo && d < hi) atomicAdd(&deg[d], 1);
        }
    }
}

// single-block full scan: rowp (exclusive, rowp[n]=E) + fillp copy
__global__ void k_scan_all(const int* __restrict__ deg, int* __restrict__ rowp,
                           int* __restrict__ fillp, int n) {
    __shared__ int sh[1024];
    int t = threadIdx.x;
    int C = (n + 1023) >> 10;
    int lo = t * C;
    int hi = lo + C; if (hi > n) hi = n;
    int s = 0;
    for (int i = lo; i < hi; ++i) s += deg[i];
    sh[t] = s;
    __syncthreads();
    for (int off = 1; off < 1024; off <<= 1) {
        int x = sh[t];
        int y = (t >= off) ? sh[t - off] : 0;
        __syncthreads();
        sh[t] = x + y;
        __syncthreads();
    }
    int run = (t == 0) ? 0 : sh[t - 1];
    for (int i = lo; i < hi; ++i) {
        rowp[i] = run;
        fillp[i] = run;
        run += deg[i];
    }
    if (hi == n && lo <= n) rowp[n] = run;
}

__global__ void k_fill(const int* __restrict__ ei, int E,
                       int* __restrict__ fillpos, int* __restrict__ colx, int npr) {
    int r  = blockIdx.x & 7;
    int lo = r * npr, hi = lo + npr;
    int nb = gridDim.x >> 3;
    int bi = blockIdx.x >> 3;
    int tid = bi * blockDim.x + threadIdx.x;
    int stride = nb * blockDim.x;
    if ((E & 3) == 0) {
        const int4* s4 = (const int4*)ei;
        const int4* d4 = (const int4*)(ei + E);
        int nch = E >> 2;
        for (int c = tid; c < nch; c += stride) {
            int4 d = d4[c];
            bool m0 = d.x >= lo && d.x < hi;
            bool m1 = d.y >= lo && d.y < hi;
            bool m2 = d.z >= lo && d.z < hi;
            bool m3 = d.w >= lo && d.w < hi;
            if (m0 | m1 | m2 | m3) {
                int4 s = s4[c];
                if (m0) colx[atomicAdd(&fillpos[d.x], 1)] = s.x;
                if (m1) colx[atomicAdd(&fillpos[d.y], 1)] = s.y;
                if (m2) colx[atomicAdd(&fillpos[d.z], 1)] = s.z;
                if (m3) colx[atomicAdd(&fillpos[d.w], 1)] = s.w;
            }
        }
    } else {
        for (int e = tid; e < E; e += stride) {
            int d = ei[E + e];
            if (d >= lo && d < hi) colx[atomicAdd(&fillpos[d], 1)] = ei[e];
        }
    }
}

// ---------------- fused prep: weights (transpose + fp32->bf16 hi/lo) and x repack ----------------

__global__ void k_prep(const float* __restrict__ x,
                       const float* __restrict__ W_in,
                       const float* __restrict__ W_self,
                       const float* __restrict__ W_nbr,
                       u16* __restrict__ xf,
                       u16* __restrict__ WtI_hi, u16* __restrict__ WtI_lo,
                       u16* __restrict__ WtS_hi, u16* __restrict__ WtS_lo,
                       u16* __restrict__ WtN_hi, u16* __restrict__ WtN_lo,
                       int L, int nxg) {
    int nIn = 64 * 128;
    int nSq = L * 128 * 128;
    int wtot = nIn + 2 * nSq;
    int total = wtot + nxg;
    int stride = gridDim.x * blockDim.x;
    for (int i = blockIdx.x * blockDim.x + threadIdx.x; i < total; i += stride) {
        if (i >= wtot) {
            // x repack: 8 cols per thread -> one contiguous frag-major ushort8 (KF=2)
            int t = i - wtot;
            int row = t >> 3, c = t & 7;
            const float4* xs = (const float4*)(x + (size_t)row * 64 + c * 8);
            float4 v0 = xs[0], v1 = xs[1];
            ushort8_t o;
            o[0] = f2bf(v0.x); o[1] = f2bf(v0.y); o[2] = f2bf(v0.z); o[3] = f2bf(v0.w);
            o[4] = f2bf(v1.x); o[5] = f2bf(v1.y); o[6] = f2bf(v1.z); o[7] = f2bf(v1.w);
            int T = row >> 4, m = row & 15;
            int f = c >> 2, q = c & 3;
            *(ushort8_t*)&xf[((size_t)(T * 2 + f) * 64 + q * 16 + m) * 8] = o;
        } else {
            float v; u16* phi; u16* plo; int o;
            if (i < nIn) {
                int n = i / 64, k = i % 64;
                v = W_in[k * 128 + n]; phi = WtI_hi; plo = WtI_lo; o = n * 64 + k;
            } else if (i < nIn + nSq) {
                int t = i - nIn;
                int l = t / (128 * 128), r = t % (128 * 128);
                int n = r / 128, k = r % 128;
                v = W_self[l * 128 * 128 + k * 128 + n]; phi = WtS_hi; plo = WtS_lo;
                o = l * 128 * 128 + n * 128 + k;
            } else {
                int t = i - nIn - nSq;
                int l = t / (128 * 128), r = t % (128 * 128);
                int n = r / 128, k = r % 128;
                v = W_nbr[l * 128 * 128 + k * 128 + n]; phi = WtN_hi; plo = WtN_lo;
                o = l * 128 * 128 + n * 128 + k;
            }
            u16 hi = f2bf(v);
            phi[o] = hi;
            plo[o] = f2bf(v - bf2f(hi));
        }
    }
}

// ---------------- input-projection GEMM (frag-major A, register-persistent B, prefetch) ----

template <int KF1, int DO_ELU>
__global__ __launch_bounds__(256, 2) void k_gemm_mfma(
    const u16* __restrict__ A1f,
    const u16* __restrict__ B1h, const u16* __restrict__ B1l,
    const float* __restrict__ bias, float* __restrict__ C,
    u16* __restrict__ Hrow, u16* __restrict__ Hf,
    int M)
{
    constexpr int K1 = KF1 * 32;
    constexpr int KF = KF1;
    int lane = threadIdx.x & 63;
    int w    = threadIdx.x >> 6;
    int m16  = lane & 15;
    int quad = lane >> 4;
    int kq   = quad * 8;
    int ng   = (blockIdx.x >> 3) & 1;
    int mtb  = (blockIdx.x & 7) | ((blockIdx.x >> 4) << 3);   // [0, gridDim/2)
    int ncol = (ng * 4 + w) * 16 + m16;

    frag_t bh[KF], bl[KF];
#pragma unroll
    for (int f = 0; f < KF; ++f) {
        bh[f] = *(const frag_t*)&B1h[(size_t)ncol * K1 + f * 32 + kq];
        bl[f] = *(const frag_t*)&B1l[(size_t)ncol * K1 + f * 32 + kq];
    }

    float bv = bias[ncol];
    int nMT  = (M + 31) >> 5;
    int step = gridDim.x >> 1;
    int fcol = ncol >> 5;
    int qcol = (ncol & 31) >> 3;
    int jcol = ncol & 7;

    auto loadA = [&](int mt, frag_t (&a0)[KF], frag_t (&a1)[KF]) {
        int T0 = mt * 2, T1 = T0 + 1;
#pragma unroll
        for (int f = 0; f < KF; ++f) {
            a0[f] = *(const frag_t*)&A1f[((size_t)(T0 * KF1 + f) * 64 + lane) * 8];
            a1[f] = *(const frag_t*)&A1f[((size_t)(T1 * KF1 + f) * 64 + lane) * 8];
        }
    };

    auto compute = [&](int mt, frag_t (&a0)[KF], frag_t (&a1)[KF]) {
        f32x4_t acc0 = (f32x4_t){0.f, 0.f, 0.f, 0.f};
        f32x4_t acc1 = (f32x4_t){0.f, 0.f, 0.f, 0.f};
#pragma unroll
        for (int f = 0; f < KF; ++f) {
            acc0 = __builtin_amdgcn_mfma_f32_16x16x32_bf16(a0[f], bh[f], acc0, 0, 0, 0);
            acc1 = __builtin_amdgcn_mfma_f32_16x16x32_bf16(a1[f], bh[f], acc1, 0, 0, 0);
            acc0 = __builtin_amdgcn_mfma_f32_16x16x32_bf16(a0[f], bl[f], acc0, 0, 0, 0);
            acc1 = __builtin_amdgcn_mfma_f32_16x16x32_bf16(a1[f], bl[f], acc1, 0, 0, 0);
        }
        int rb = mt * 32 + quad * 4;
#pragma unroll
        for (int r = 0; r < 4; ++r) {
#pragma unroll
            for (int half = 0; half < 2; ++half) {
                int row = rb + r + half * 16;
                float av = half ? acc1[r] : acc0[r];
                if (row < M) {
                    float v = av + bv;
                    if constexpr (DO_ELU) v = (v > 0.f) ? v : expm1f(v);
                    if (C) C[(size_t)row * HIDDEN + ncol] = v;
                    if (Hrow) {
                        u16 hv = f2bf(v);
                        Hrow[(size_t)row * HIDDEN + ncol] = hv;
                        Hf[((size_t)((row >> 4) * 4 + fcol) * 64 + qcol * 16 + (row & 15)) * 8 + jcol] = hv;
                    }
                }
            }
        }
    };

    int mt = mtb;
    if (mt >= nMT) return;
    frag_t xa0[KF], xa1[KF], ya0[KF], ya1[KF];
    loadA(mt, xa0, xa1);
    while (true) {
        int mt2 = mt + step;
        if (mt2 < nMT) loadA(mt2, ya0, ya1);
        compute(mt, xa0, xa1);
        if (mt2 >= nMT) break;
        int mt3 = mt2 + step;
        if (mt3 < nMT) loadA(mt3, xa0, xa1);
        compute(mt2, ya0, ya1);
        if (mt3 >= nMT) break;
        mt = mt3;
    }
}

// ---------------- fused layer kernel: agg (gather-mean into LDS) + dual-K GEMM ----
// 512 threads = 8 waves; wave w owns output cols w*16+m16 (all 128 cols in one block),
// so the agg for a tile's 32 rows is computed exactly once by the block that consumes it.
// LDS double-buffer, one barrier per tile. MFMA order identical to previous k_gemm<4,4>.

template <int DO_ELU>
__global__ __launch_bounds__(512, 2) void k_layer(
    const ushort8_t* __restrict__ hb8,   // row-major bf16 h (gather source)
    const u16* __restrict__ Af,          // frag-major h (KF=4) self A-operand
    const int* __restrict__ rowp, const int* __restrict__ colx,
    const u16* __restrict__ Bsh, const u16* __restrict__ Bsl,
    const u16* __restrict__ Bnh, const u16* __restrict__ Bnl,
    const float* __restrict__ bias,
    float* __restrict__ C, u16* __restrict__ Hrow, u16* __restrict__ Hf,
    int M)
{
    constexpr int KF1 = 4, KF2 = 4, KF = 8;
    __shared__ u16 lds_sf[2][2 * KF2 * 64 * 8];   // 2 bufs x (2 subtiles x 4 frags x 64 lanes x 8) = 16KB

    int tid  = threadIdx.x;
    int lane = tid & 63;
    int w    = tid >> 6;            // 0..7
    int m16  = lane & 15;
    int quad = lane >> 4;
    int kq   = quad * 8;
    int ncol = w * 16 + m16;        // all 128 cols covered by the 8 waves

    // persistent B fragments (hi+lo): [0..3]=self, [4..7]=nbr (same order as before)
    frag_t bh[KF], bl[KF];
#pragma unroll
    for (int f = 0; f < KF1; ++f) {
        bh[f] = *(const frag_t*)&Bsh[(size_t)ncol * 128 + f * 32 + kq];
        bl[f] = *(const frag_t*)&Bsl[(size_t)ncol * 128 + f * 32 + kq];
    }
#pragma unroll
    for (int f = 0; f < KF2; ++f) {
        bh[KF1 + f] = *(const frag_t*)&Bnh[(size_t)ncol * 128 + f * 32 + kq];
        bl[KF1 + f] = *(const frag_t*)&Bnl[(size_t)ncol * 128 + f * 32 + kq];
    }
    float bv = bias[ncol];

    // agg mapping: 16 lanes per node, 32 nodes per tile
    int anode = tid >> 4;           // local row 0..31
    int alane = tid & 15;           // cols alane*8 .. alane*8+7
    // LDS store coords (frag-major within tile)
    int sOff = ((((anode >> 4) * 4 + (alane >> 2)) * 64) + (alane & 3) * 16 + (anode & 15)) * 8;

    int nMT  = (M + 31) >> 5;
    int fcol = ncol >> 5;
    int qcol = (ncol & 31) >> 3;
    int jcol = ncol & 7;

    int p = 0;
    for (int mt = blockIdx.x; mt < nMT; mt += gridDim.x) {
        // ---- AGG phase: gather-mean rows mt*32 .. mt*32+31 into lds_sf[p] ----
        int g = mt * 32 + anode;
        ushort8_t o;
        if (g < M) {
            int beg = rowp[g];
            int end = rowp[g + 1];
            float a0[8], a1[8];
#pragma unroll
            for (int j = 0; j < 8; ++j) { a0[j] = 0.f; a1[j] = 0.f; }
            int e = beg;
            for (; e + 7 < end; e += 8) {
                int s0 = colx[e],     s1 = colx[e + 1], s2 = colx[e + 2], s3 = colx[e + 3];
                int s4 = colx[e + 4], s5 = colx[e + 5], s6 = colx[e + 6], s7 = colx[e + 7];
                ushort8_t v0 = hb8[(size_t)s0 * 16 + alane];
                ushort8_t v1 = hb8[(size_t)s1 * 16 + alane];
                ushort8_t v2 = hb8[(size_t)s2 * 16 + alane];
                ushort8_t v3 = hb8[(size_t)s3 * 16 + alane];
                ushort8_t v4 = hb8[(size_t)s4 * 16 + alane];
                ushort8_t v5 = hb8[(size_t)s5 * 16 + alane];
                ushort8_t v6 = hb8[(size_t)s6 * 16 + alane];
                ushort8_t v7 = hb8[(size_t)s7 * 16 + alane];
#pragma unroll
                for (int j = 0; j < 8; ++j) {
                    a0[j] += bf2f(v0[j]); a1[j] += bf2f(v1[j]);
                    a0[j] += bf2f(v2[j]); a1[j] += bf2f(v3[j]);
                    a0[j] += bf2f(v4[j]); a1[j] += bf2f(v5[j]);
                    a0[j] += bf2f(v6[j]); a1[j] += bf2f(v7[j]);
                }
            }
            for (; e + 3 < end; e += 4) {
                int s0 = colx[e], s1 = colx[e + 1], s2 = colx[e + 2], s3 = colx[e + 3];
                ushort8_t v0 = hb8[(size_t)s0 * 16 + alane];
                ushort8_t v1 = hb8[(size_t)s1 * 16 + alane];
                ushort8_t v2 = hb8[(size_t)s2 * 16 + alane];
                ushort8_t v3 = hb8[(size_t)s3 * 16 + alane];
#pragma unroll
                for (int j = 0; j < 8; ++j) {
                    a0[j] += bf2f(v0[j]); a1[j] += bf2f(v1[j]);
                    a0[j] += bf2f(v2[j]); a1[j] += bf2f(v3[j]);
                }
            }
            for (; e < end; ++e) {
                int s = colx[e];
                ushort8_t v = hb8[(size_t)s * 16 + alane];
#pragma unroll
                for (int j = 0; j < 8; ++j) a0[j] += bf2f(v[j]);
            }
            int deg = end - beg;
            float inv = 1.0f / (float)(deg > 1 ? deg : 1);
#pragma unroll
            for (int j = 0; j < 8; ++j) o[j] = f2bf((a0[j] + a1[j]) * inv);
        } else {
#pragma unroll
            for (int j = 0; j < 8; ++j) o[j] = 0;
        }
        *(ushort8_t*)&lds_sf[p][sOff] = o;

        // self A-operand frag loads (global, issued before barrier -> in flight across it)
        int T0 = mt * 2, T1 = T0 + 1;
        frag_t a0f[KF], a1f[KF];
#pragma unroll
        for (int f = 0; f < KF1; ++f) {
            a0f[f] = *(const frag_t*)&Af[((size_t)(T0 * KF1 + f) * 64 + lane) * 8];
            a1f[f] = *(const frag_t*)&Af[((size_t)(T1 * KF1 + f) * 64 + lane) * 8];
        }

        __syncthreads();

        // nbr A-operand frags from LDS
#pragma unroll
        for (int f = 0; f < KF2; ++f) {
            a0f[KF1 + f] = *(const frag_t*)&lds_sf[p][((0 * 4 + f) * 64 + lane) * 8];
            a1f[KF1 + f] = *(const frag_t*)&lds_sf[p][((1 * 4 + f) * 64 + lane) * 8];
        }

        // ---- MFMA phase (order identical to previous k_gemm<4,4>) ----
        f32x4_t acc0 = (f32x4_t){0.f, 0.f, 0.f, 0.f};
        f32x4_t acc1 = (f32x4_t){0.f, 0.f, 0.f, 0.f};
#pragma unroll
        for (int f = 0; f < KF; ++f) {
            acc0 = __builtin_amdgcn_mfma_f32_16x16x32_bf16(a0f[f], bh[f], acc0, 0, 0, 0);
            acc1 = __builtin_amdgcn_mfma_f32_16x16x32_bf16(a1f[f], bh[f], acc1, 0, 0, 0);
            acc0 = __builtin_amdgcn_mfma_f32_16x16x32_bf16(a0f[f], bl[f], acc0, 0, 0, 0);
            acc1 = __builtin_amdgcn_mfma_f32_16x16x32_bf16(a1f[f], bl[f], acc1, 0, 0, 0);
        }

        // epilogue: C/D layout col = lane&15, row = quad*4 + reg
        int rb = mt * 32 + quad * 4;
#pragma unroll
        for (int r = 0; r < 4; ++r) {
#pragma unroll
            for (int half = 0; half < 2; ++half) {
                int row = rb + r + half * 16;
                float av = half ? acc1[r] : acc0[r];
                if (row < M) {
                    float v = av + bv;
                    if constexpr (DO_ELU) v = (v > 0.f) ? v : expm1f(v);
                    if (C) C[(size_t)row * HIDDEN + ncol] = v;
                    if (Hrow) {
                        u16 hv = f2bf(v);
                        Hrow[(size_t)row * HIDDEN + ncol] = hv;
                        Hf[((size_t)((row >> 4) * 4 + fcol) * 64 + qcol * 16 + (row & 15)) * 8 + jcol] = hv;
                    }
                }
            }
        }
        p ^= 1;
    }
}

// ---------------- launch ----------------

extern "C" void kernel_launch(void* const* d_in, const int* in_sizes, int n_in,
                              void* d_out, int out_size, void* d_ws, size_t ws_size,
                              hipStream_t stream) {
    const float* x        = (const float*)d_in[0];
    const int* ei         = (const int*)d_in[1];
    const float* W_in     = (const float*)d_in[2];
    const float* b_in     = (const float*)d_in[3];
    const float* W_self   = (const float*)d_in[4];
    const float* b_self   = (const float*)d_in[5];
    const float* W_nbr    = (const float*)d_in[6];
    float* out = (float*)d_out;

    const int IN_FEAT = 64;
    int N = in_sizes[0] / IN_FEAT;           // 50000
    int E = in_sizes[1] / 2;                 // 800000
    int L = in_sizes[4] / (HIDDEN * HIDDEN); // 3

    char* ws = (char*)d_ws;
    size_t off = 0;
    auto alloc = [&](size_t bytes) -> void* {
        void* p = ws + off;
        off = (off + bytes + 255) & ~(size_t)255;
        return p;
    };

    int nT = ((N + 31) / 32) * 2;            // 16-row tiles, padded to macro-tile pairs

    u16* hRowA = (u16*)alloc((size_t)N * HIDDEN * 2);
    u16* hRowB = (u16*)alloc((size_t)N * HIDDEN * 2);
    u16* hfA   = (u16*)alloc((size_t)nT * 4 * 64 * 8 * 2);   // KF=4 frag-major
    u16* hfB   = (u16*)alloc((size_t)nT * 4 * 64 * 8 * 2);
    u16* xf    = (u16*)alloc((size_t)nT * 2 * 64 * 8 * 2);   // KF=2
    u16* WtI_hi = (u16*)alloc(128 * 64 * 2);
    u16* WtI_lo = (u16*)alloc(128 * 64 * 2);
    u16* WtS_hi = (u16*)alloc((size_t)L * 128 * 128 * 2);
    u16* WtS_lo = (u16*)alloc((size_t)L * 128 * 128 * 2);
    u16* WtN_hi = (u16*)alloc((size_t)L * 128 * 128 * 2);
    u16* WtN_lo = (u16*)alloc((size_t)L * 128 * 128 * 2);
    int* deg   = (int*)alloc((size_t)N * sizeof(int));
    int* rowp  = (int*)alloc((size_t)(N + 1) * sizeof(int));
    int* fillp = (int*)alloc((size_t)N * sizeof(int));
    int* colx  = (int*)alloc((size_t)E * sizeof(int));

    int npr = (N + 7) / 8;   // nodes per XCD range

    // CSR build (XCD-range-partitioned scatters; single-kernel scan)
    hipMemsetAsync(deg, 0, (size_t)N * sizeof(int), stream);
    k_hist<<<2048, 256, 0, stream>>>(ei, E, deg, npr);
    k_scan_all<<<1, 1024, 0, stream>>>(deg, rowp, fillp, N);
    k_fill<<<2048, 256, 0, stream>>>(ei, E, fillp, colx, npr);

    // fused prep (weights + x repack)
    int wtot = 64 * 128 + 2 * L * 128 * 128;
    int prep_total = wtot + N * 8;
    k_prep<<<(prep_total + 255) / 256, 256, 0, stream>>>(
        x, W_in, W_self, W_nbr, xf,
        WtI_hi, WtI_lo, WtS_hi, WtS_lo, WtN_hi, WtN_lo, L, N * 8);

    // input projection: h = bf16(x @ W_in + b_in)  -> hRowA + hfA
    k_gemm_mfma<2, 0><<<1024, 256, 0, stream>>>(
        xf, WtI_hi, WtI_lo, b_in, nullptr, hRowA, hfA, N);

    u16* curRow = hRowA; u16* curF = hfA;
    u16* nxtRow = hRowB; u16* nxtF = hfB;

    for (int l = 0; l < L; ++l) {
        const u16* Wsh = WtS_hi + (size_t)l * 128 * 128;
        const u16* Wsl = WtS_lo + (size_t)l * 128 * 128;
        const u16* Wnh = WtN_hi + (size_t)l * 128 * 128;
        const u16* Wnl = WtN_lo + (size_t)l * 128 * 128;
        const float* bs = b_self + (size_t)l * HIDDEN;
        bool last = (l == L - 1);
        k_layer<1><<<512, 512, 0, stream>>>(
            (const ushort8_t*)curRow, curF, rowp, colx,
            Wsh, Wsl, Wnh, Wnl, bs,
            last ? out : nullptr,
            last ? nullptr : nxtRow, last ? nullptr : nxtF, N);
        u16* tr = curRow; curRow = nxtRow; nxtRow = tr;
        u16* tf = curF;   curF = nxtF;     nxtF = tf;
    }
}

// Round 3
// 333.123 us; speedup vs baseline: 1.4076x; 1.4076x over previous
//
#include <hip/hip_runtime.h>
#include <cstdint>

#define HIDDEN 128

typedef unsigned short u16;
using frag_t   = __attribute__((ext_vector_type(8))) short;   // 8 bf16 (4 VGPRs)
using f32x4_t  = __attribute__((ext_vector_type(4))) float;   // MFMA accumulator
using ushort8_t = __attribute__((ext_vector_type(8))) unsigned short;

__device__ __forceinline__ float bf2f(u16 u) {
    union { unsigned int i; float f; } c;
    c.i = ((unsigned int)u) << 16;
    return c.f;
}
__device__ __forceinline__ u16 f2bf(float f) {
    unsigned int u = __float_as_uint(f);
    unsigned int r = (u + 0x7fffu + ((u >> 16) & 1u)) >> 16;   // RNE
    return (u16)r;
}

// ---------------- CSR build + prep fused (edge_index arrives as int32 from harness) ----------------
// XCD-range partitioning: blocks with blockIdx&7==r own dst range [r*npr, (r+1)*npr).
// Prep work (weight transpose/split + x repack) is independent of CSR; distributed over the same grid.

__global__ void k_hist_prep(const int* __restrict__ ei, int E, int* __restrict__ deg, int npr,
                            const float* __restrict__ x,
                            const float* __restrict__ W_in,
                            const float* __restrict__ W_self,
                            const float* __restrict__ W_nbr,
                            u16* __restrict__ xf,
                            u16* __restrict__ WtI_hi, u16* __restrict__ WtI_lo,
                            u16* __restrict__ WtS_hi, u16* __restrict__ WtS_lo,
                            u16* __restrict__ WtN_hi, u16* __restrict__ WtN_lo,
                            int L, int nxg) {
    // ---- histogram part ----
    {
        int r  = blockIdx.x & 7;
        int lo = r * npr, hi = lo + npr;
        int nb = gridDim.x >> 3;
        int bi = blockIdx.x >> 3;
        int tid = bi * blockDim.x + threadIdx.x;
        int stride = nb * blockDim.x;
        if ((E & 3) == 0) {
            const int4* d4 = (const int4*)(ei + E);
            int nch = E >> 2;
            for (int c = tid; c < nch; c += stride) {
                int4 d = d4[c];
                if (d.x >= lo && d.x < hi) atomicAdd(&deg[d.x], 1);
                if (d.y >= lo && d.y < hi) atomicAdd(&deg[d.y], 1);
                if (d.z >= lo && d.z < hi) atomicAdd(&deg[d.z], 1);
                if (d.w >= lo && d.w < hi) atomicAdd(&deg[d.w], 1);
            }
        } else {
            for (int e = tid; e < E; e += stride) {
                int d = ei[E + e];
                if (d >= lo && d < hi) atomicAdd(&deg[d], 1);
            }
        }
    }
    // ---- prep part ----
    {
        int nIn = 64 * 128;
        int nSq = L * 128 * 128;
        int wtot = nIn + 2 * nSq;
        int total = wtot + nxg;
        int stride = gridDim.x * blockDim.x;
        for (int i = blockIdx.x * blockDim.x + threadIdx.x; i < total; i += stride) {
            if (i >= wtot) {
                // x repack: 8 cols per thread -> one contiguous frag-major ushort8 (KF=2)
                int t = i - wtot;
                int row = t >> 3, c = t & 7;
                const float4* xs = (const float4*)(x + (size_t)row * 64 + c * 8);
                float4 v0 = xs[0], v1 = xs[1];
                ushort8_t o;
                o[0] = f2bf(v0.x); o[1] = f2bf(v0.y); o[2] = f2bf(v0.z); o[3] = f2bf(v0.w);
                o[4] = f2bf(v1.x); o[5] = f2bf(v1.y); o[6] = f2bf(v1.z); o[7] = f2bf(v1.w);
                int T = row >> 4, m = row & 15;
                int f = c >> 2, q = c & 3;
                *(ushort8_t*)&xf[((size_t)(T * 2 + f) * 64 + q * 16 + m) * 8] = o;
            } else {
                float v; u16* phi; u16* plo; int o;
                if (i < nIn) {
                    int n = i / 64, k = i % 64;
                    v = W_in[k * 128 + n]; phi = WtI_hi; plo = WtI_lo; o = n * 64 + k;
                } else if (i < nIn + nSq) {
                    int t = i - nIn;
                    int l = t / (128 * 128), r = t % (128 * 128);
                    int n = r / 128, k = r % 128;
                    v = W_self[l * 128 * 128 + k * 128 + n]; phi = WtS_hi; plo = WtS_lo;
                    o = l * 128 * 128 + n * 128 + k;
                } else {
                    int t = i - nIn - nSq;
                    int l = t / (128 * 128), r = t % (128 * 128);
                    int n = r / 128, k = r % 128;
                    v = W_nbr[l * 128 * 128 + k * 128 + n]; phi = WtN_hi; plo = WtN_lo;
                    o = l * 128 * 128 + n * 128 + k;
                }
                u16 hi = f2bf(v);
                phi[o] = hi;
                plo[o] = f2bf(v - bf2f(hi));
            }
        }
    }
}

__global__ void k_scan1(const int* __restrict__ deg, int* __restrict__ rowp,
                        int* __restrict__ bsums, int n) {
    __shared__ int sh[1024];
    int t = threadIdx.x;
    int base = blockIdx.x * 1024;
    int v = (base + t < n) ? deg[base + t] : 0;
    sh[t] = v;
    __syncthreads();
    for (int off = 1; off < 1024; off <<= 1) {
        int x = sh[t];
        int y = (t >= off) ? sh[t - off] : 0;
        __syncthreads();
        sh[t] = x + y;
        __syncthreads();
    }
    if (base + t < n) rowp[base + t + 1] = sh[t];
    if (t == 1023) bsums[blockIdx.x] = sh[1023];
}

// merged scan2+scan3: each block locally re-scans the (small) bsums array in LDS,
// derives its own exclusive offset, then applies it + writes fillp.
__global__ void k_scan_tail(int* __restrict__ rowp, const int* __restrict__ bsums,
                            int* __restrict__ fillp, int n, int nb) {
    __shared__ int sh[1024];
    int t = threadIdx.x;
    int b = blockIdx.x;
    sh[t] = (t < nb) ? bsums[t] : 0;
    __syncthreads();
    for (int off = 1; off < 1024; off <<= 1) {
        int x = sh[t];
        int y = (t >= off) ? sh[t - off] : 0;
        __syncthreads();
        sh[t] = x + y;
        __syncthreads();
    }
    int boff = (b == 0) ? 0 : sh[b - 1];   // exclusive prefix of bsums at b
    int base = b * 1024;
    if (base + t < n) {
        int v = rowp[base + t + 1] + boff;
        rowp[base + t + 1] = v;
        if (base + t + 1 < n) fillp[base + t + 1] = v;
    }
    if (b == 0 && t == 0) { rowp[0] = 0; fillp[0] = 0; }
}

__global__ void k_fill(const int* __restrict__ ei, int E,
                       int* __restrict__ fillpos, int* __restrict__ colx, int npr) {
    int r  = blockIdx.x & 7;
    int lo = r * npr, hi = lo + npr;
    int nb = gridDim.x >> 3;
    int bi = blockIdx.x >> 3;
    int tid = bi * blockDim.x + threadIdx.x;
    int stride = nb * blockDim.x;
    if ((E & 3) == 0) {
        const int4* s4 = (const int4*)ei;
        const int4* d4 = (const int4*)(ei + E);
        int nch = E >> 2;
        for (int c = tid; c < nch; c += stride) {
            int4 d = d4[c];
            bool m0 = d.x >= lo && d.x < hi;
            bool m1 = d.y >= lo && d.y < hi;
            bool m2 = d.z >= lo && d.z < hi;
            bool m3 = d.w >= lo && d.w < hi;
            if (m0 | m1 | m2 | m3) {
                int4 s = s4[c];
                if (m0) colx[atomicAdd(&fillpos[d.x], 1)] = s.x;
                if (m1) colx[atomicAdd(&fillpos[d.y], 1)] = s.y;
                if (m2) colx[atomicAdd(&fillpos[d.z], 1)] = s.z;
                if (m3) colx[atomicAdd(&fillpos[d.w], 1)] = s.w;
            }
        }
    } else {
        for (int e = tid; e < E; e += stride) {
            int d = ei[E + e];
            if (d >= lo && d < hi) colx[atomicAdd(&fillpos[d], 1)] = ei[e];
        }
    }
}

// ---------------- aggregation: Sf = bf16(mean over CSR row of hb rows), fragment-major out ----
// 16 lanes/node, 16B (ushort8) gathers.

__global__ __launch_bounds__(256, 4) void k_agg(
        const ushort8_t* __restrict__ hb8, const int* __restrict__ rowp,
        const int* __restrict__ colx, u16* __restrict__ Sf, int n) {
    int g = (blockIdx.x * blockDim.x + threadIdx.x) >> 4;   // 16 lanes/node, lane = 8 cols
    int lane = threadIdx.x & 15;
    if (g >= n) return;
    int beg = rowp[g];
    int end = rowp[g + 1];
    float a0[8], a1[8];
#pragma unroll
    for (int j = 0; j < 8; ++j) { a0[j] = 0.f; a1[j] = 0.f; }
    int e = beg;
    for (; e + 7 < end; e += 8) {
        int s0 = colx[e],     s1 = colx[e + 1], s2 = colx[e + 2], s3 = colx[e + 3];
        int s4 = colx[e + 4], s5 = colx[e + 5], s6 = colx[e + 6], s7 = colx[e + 7];
        ushort8_t v0 = hb8[(size_t)s0 * 16 + lane];
        ushort8_t v1 = hb8[(size_t)s1 * 16 + lane];
        ushort8_t v2 = hb8[(size_t)s2 * 16 + lane];
        ushort8_t v3 = hb8[(size_t)s3 * 16 + lane];
        ushort8_t v4 = hb8[(size_t)s4 * 16 + lane];
        ushort8_t v5 = hb8[(size_t)s5 * 16 + lane];
        ushort8_t v6 = hb8[(size_t)s6 * 16 + lane];
        ushort8_t v7 = hb8[(size_t)s7 * 16 + lane];
#pragma unroll
        for (int j = 0; j < 8; ++j) {
            a0[j] += bf2f(v0[j]); a1[j] += bf2f(v1[j]);
            a0[j] += bf2f(v2[j]); a1[j] += bf2f(v3[j]);
            a0[j] += bf2f(v4[j]); a1[j] += bf2f(v5[j]);
            a0[j] += bf2f(v6[j]); a1[j] += bf2f(v7[j]);
        }
    }
    for (; e + 3 < end; e += 4) {
        int s0 = colx[e], s1 = colx[e + 1], s2 = colx[e + 2], s3 = colx[e + 3];
        ushort8_t v0 = hb8[(size_t)s0 * 16 + lane];
        ushort8_t v1 = hb8[(size_t)s1 * 16 + lane];
        ushort8_t v2 = hb8[(size_t)s2 * 16 + lane];
        ushort8_t v3 = hb8[(size_t)s3 * 16 + lane];
#pragma unroll
        for (int j = 0; j < 8; ++j) {
            a0[j] += bf2f(v0[j]); a1[j] += bf2f(v1[j]);
            a0[j] += bf2f(v2[j]); a1[j] += bf2f(v3[j]);
        }
    }
    for (; e < end; ++e) {
        int s = colx[e];
        ushort8_t v = hb8[(size_t)s * 16 + lane];
#pragma unroll
        for (int j = 0; j < 8; ++j) a0[j] += bf2f(v[j]);
    }
    int deg = end - beg;
    float inv = 1.0f / (float)(deg > 1 ? deg : 1);
    ushort8_t o;
#pragma unroll
    for (int j = 0; j < 8; ++j) o[j] = f2bf((a0[j] + a1[j]) * inv);
    // fragment-major store (KF=4): lane's cols lane*8..lane*8+7 = one contiguous j-group
    int T = g >> 4, m = g & 15;
    *(ushort8_t*)&Sf[((size_t)(T * 4 + (lane >> 2)) * 64 + (lane & 3) * 16 + m) * 8] = o;
}

// ---------------- MFMA GEMM: frag-major A, register-persistent B, A-tile prefetch ----
// ng = (blockIdx>>3)&1 : XCD-paired col-halves share A rows in L2.

template <int KF1, int KF2, int DO_ELU>
__global__ __launch_bounds__(256, 2) void k_gemm_mfma(
    const u16* __restrict__ A1f, const u16* __restrict__ A2f,
    const u16* __restrict__ B1h, const u16* __restrict__ B1l,
    const u16* __restrict__ B2h, const u16* __restrict__ B2l,
    const float* __restrict__ bias, float* __restrict__ C,
    u16* __restrict__ Hrow, u16* __restrict__ Hf,
    int M)
{
    constexpr int K1 = KF1 * 32;
    constexpr int K2 = KF2 * 32;
    constexpr int KF = KF1 + KF2;
    int lane = threadIdx.x & 63;
    int w    = threadIdx.x >> 6;
    int m16  = lane & 15;
    int quad = lane >> 4;
    int kq   = quad * 8;
    int ng   = (blockIdx.x >> 3) & 1;
    int mtb  = (blockIdx.x & 7) | ((blockIdx.x >> 4) << 3);   // [0, gridDim/2)
    int ncol = (ng * 4 + w) * 16 + m16;     // this lane's output column (B row)

    frag_t bh[KF], bl[KF];
    if constexpr (KF1 > 0) {
#pragma unroll
        for (int f = 0; f < KF1; ++f) {
            bh[f] = *(const frag_t*)&B1h[(size_t)ncol * K1 + f * 32 + kq];
            bl[f] = *(const frag_t*)&B1l[(size_t)ncol * K1 + f * 32 + kq];
        }
    }
    if constexpr (KF2 > 0) {
#pragma unroll
        for (int f = 0; f < KF2; ++f) {
            bh[KF1 + f] = *(const frag_t*)&B2h[(size_t)ncol * K2 + f * 32 + kq];
            bl[KF1 + f] = *(const frag_t*)&B2l[(size_t)ncol * K2 + f * 32 + kq];
        }
    }

    float bv = bias[ncol];
    int nMT  = (M + 31) >> 5;
    int step = gridDim.x >> 1;
    int fcol = ncol >> 5;            // Hf store coords (KFout = 4)
    int qcol = (ncol & 31) >> 3;
    int jcol = ncol & 7;

    auto loadA = [&](int mt, frag_t (&a0)[KF], frag_t (&a1)[KF]) {
        int T0 = mt * 2, T1 = T0 + 1;   // padded alloc: no guards
        if constexpr (KF1 > 0) {
#pragma unroll
            for (int f = 0; f < KF1; ++f) {
                a0[f] = *(const frag_t*)&A1f[((size_t)(T0 * KF1 + f) * 64 + lane) * 8];
                a1[f] = *(const frag_t*)&A1f[((size_t)(T1 * KF1 + f) * 64 + lane) * 8];
            }
        }
        if constexpr (KF2 > 0) {
#pragma unroll
            for (int f = 0; f < KF2; ++f) {
                a0[KF1 + f] = *(const frag_t*)&A2f[((size_t)(T0 * KF2 + f) * 64 + lane) * 8];
                a1[KF1 + f] = *(const frag_t*)&A2f[((size_t)(T1 * KF2 + f) * 64 + lane) * 8];
            }
        }
    };

    auto compute = [&](int mt, frag_t (&a0)[KF], frag_t (&a1)[KF]) {
        f32x4_t acc0 = (f32x4_t){0.f, 0.f, 0.f, 0.f};
        f32x4_t acc1 = (f32x4_t){0.f, 0.f, 0.f, 0.f};
#pragma unroll
        for (int f = 0; f < KF; ++f) {
            acc0 = __builtin_amdgcn_mfma_f32_16x16x32_bf16(a0[f], bh[f], acc0, 0, 0, 0);
            acc1 = __builtin_amdgcn_mfma_f32_16x16x32_bf16(a1[f], bh[f], acc1, 0, 0, 0);
            acc0 = __builtin_amdgcn_mfma_f32_16x16x32_bf16(a0[f], bl[f], acc0, 0, 0, 0);
            acc1 = __builtin_amdgcn_mfma_f32_16x16x32_bf16(a1[f], bl[f], acc1, 0, 0, 0);
        }
        int rb = mt * 32 + quad * 4;
#pragma unroll
        for (int r = 0; r < 4; ++r) {
#pragma unroll
            for (int half = 0; half < 2; ++half) {
                int row = rb + r + half * 16;
                float av = half ? acc1[r] : acc0[r];
                if (row < M) {
                    float v = av + bv;
                    if constexpr (DO_ELU) v = (v > 0.f) ? v : expm1f(v);
                    if (C) C[(size_t)row * HIDDEN + ncol] = v;
                    if (Hrow) {
                        u16 hv = f2bf(v);
                        Hrow[(size_t)row * HIDDEN + ncol] = hv;
                        Hf[((size_t)((row >> 4) * 4 + fcol) * 64 + qcol * 16 + (row & 15)) * 8 + jcol] = hv;
                    }
                }
            }
        }
    };

    int mt = mtb;
    if (mt >= nMT) return;
    frag_t xa0[KF], xa1[KF], ya0[KF], ya1[KF];
    loadA(mt, xa0, xa1);
    while (true) {
        int mt2 = mt + step;
        if (mt2 < nMT) loadA(mt2, ya0, ya1);       // prefetch under compute(mt)
        compute(mt, xa0, xa1);
        if (mt2 >= nMT) break;
        int mt3 = mt2 + step;
        if (mt3 < nMT) loadA(mt3, xa0, xa1);       // prefetch under compute(mt2)
        compute(mt2, ya0, ya1);
        if (mt3 >= nMT) break;
        mt = mt3;
    }
}

// ---------------- launch ----------------

extern "C" void kernel_launch(void* const* d_in, const int* in_sizes, int n_in,
                              void* d_out, int out_size, void* d_ws, size_t ws_size,
                              hipStream_t stream) {
    const float* x        = (const float*)d_in[0];
    const int* ei         = (const int*)d_in[1];
    const float* W_in     = (const float*)d_in[2];
    const float* b_in     = (const float*)d_in[3];
    const float* W_self   = (const float*)d_in[4];
    const float* b_self   = (const float*)d_in[5];
    const float* W_nbr    = (const float*)d_in[6];
    float* out = (float*)d_out;

    const int IN_FEAT = 64;
    int N = in_sizes[0] / IN_FEAT;           // 50000
    int E = in_sizes[1] / 2;                 // 800000
    int L = in_sizes[4] / (HIDDEN * HIDDEN); // 3

    char* ws = (char*)d_ws;
    size_t off = 0;
    auto alloc = [&](size_t bytes) -> void* {
        void* p = ws + off;
        off = (off + bytes + 255) & ~(size_t)255;
        return p;
    };

    int nT = ((N + 31) / 32) * 2;            // 16-row tiles, padded to macro-tile pairs

    u16* hRowA = (u16*)alloc((size_t)N * HIDDEN * 2);
    u16* hRowB = (u16*)alloc((size_t)N * HIDDEN * 2);
    u16* hfA   = (u16*)alloc((size_t)nT * 4 * 64 * 8 * 2);   // KF=4 frag-major
    u16* hfB   = (u16*)alloc((size_t)nT * 4 * 64 * 8 * 2);
    u16* xf    = (u16*)alloc((size_t)nT * 2 * 64 * 8 * 2);   // KF=2
    u16* Sf    = (u16*)alloc((size_t)nT * 4 * 64 * 8 * 2);
    u16* WtI_hi = (u16*)alloc(128 * 64 * 2);
    u16* WtI_lo = (u16*)alloc(128 * 64 * 2);
    u16* WtS_hi = (u16*)alloc((size_t)L * 128 * 128 * 2);
    u16* WtS_lo = (u16*)alloc((size_t)L * 128 * 128 * 2);
    u16* WtN_hi = (u16*)alloc((size_t)L * 128 * 128 * 2);
    u16* WtN_lo = (u16*)alloc((size_t)L * 128 * 128 * 2);
    int* deg   = (int*)alloc((size_t)N * sizeof(int));
    int* rowp  = (int*)alloc((size_t)(N + 1) * sizeof(int));
    int* fillp = (int*)alloc((size_t)N * sizeof(int));
    int* colx  = (int*)alloc((size_t)E * sizeof(int));
    int* bsums = (int*)alloc(1024 * sizeof(int));

    int npr = (N + 7) / 8;   // nodes per XCD range

    // CSR build (XCD-range-partitioned scatters) with prep fused into hist
    hipMemsetAsync(deg, 0, (size_t)N * sizeof(int), stream);
    int wtot = 64 * 128 + 2 * L * 128 * 128;
    k_hist_prep<<<2048, 256, 0, stream>>>(ei, E, deg, npr,
                                          x, W_in, W_self, W_nbr, xf,
                                          WtI_hi, WtI_lo, WtS_hi, WtS_lo,
                                          WtN_hi, WtN_lo, L, N * 8);
    int nb = (N + 1023) / 1024;
    k_scan1<<<nb, 1024, 0, stream>>>(deg, rowp, bsums, N);
    k_scan_tail<<<nb, 1024, 0, stream>>>(rowp, bsums, fillp, N, nb);
    k_fill<<<2048, 256, 0, stream>>>(ei, E, fillp, colx, npr);

    const int GB = 1024;   // multiple of 16: ng=(b>>3)&1 XCD-paired; ~3 tiles/block for prefetch

    // input projection: h = bf16(x @ W_in + b_in)  -> hRowA + hfA
    k_gemm_mfma<2, 0, 0><<<GB, 256, 0, stream>>>(
        xf, nullptr,
        WtI_hi, WtI_lo, nullptr, nullptr,
        b_in, nullptr, hRowA, hfA, N);

    u16* curRow = hRowA; u16* curF = hfA;
    u16* nxtRow = hRowB; u16* nxtF = hfB;

    for (int l = 0; l < L; ++l) {
        k_agg<<<(N + 15) / 16, 256, 0, stream>>>((const ushort8_t*)curRow, rowp, colx, Sf, N);
        const u16* Wsh = WtS_hi + (size_t)l * 128 * 128;
        const u16* Wsl = WtS_lo + (size_t)l * 128 * 128;
        const u16* Wnh = WtN_hi + (size_t)l * 128 * 128;
        const u16* Wnl = WtN_lo + (size_t)l * 128 * 128;
        const float* bs = b_self + (size_t)l * HIDDEN;
        bool last = (l == L - 1);
        k_gemm_mfma<4, 4, 1><<<GB, 256, 0, stream>>>(
            curF, Sf,
            Wsh, Wsl, Wnh, Wnl,
            bs, last ? out : nullptr,
            last ? nullptr : nxtRow, last ? nullptr : nxtF, N);
        u16* tr = curRow; curRow = nxtRow; nxtRow = tr;
        u16* tf = curF;   curF = nxtF;     nxtF = tf;
    }
}